// Round 13
// baseline (186.162 us; speedup 1.0000x reference)
//
#include <hip/hip_runtime.h>

// Problem constants (from reference setup_inputs)
#define BB 8
#define QQ 30
#define DD 1500
#define EE 768
#define KK 11
#define WW 736      // (1500-30)/2 + 1
#define WIN 30
#define STR 2

#define NT 94       // n-tiles of 16 d (94*16 = 1504 >= 1500)
#define NBLK 256    // one block per CU worst case -> co-residency guaranteed
#define DCH 544     // windows chunk d-extent (2*255+29+1 = 540, padded)

typedef __attribute__((ext_vector_type(8))) __bf16 bf16x8;
typedef __attribute__((ext_vector_type(4))) float f32x4;
typedef __attribute__((ext_vector_type(4))) unsigned int uint4v;

__device__ inline unsigned int f2bf(float x) {   // f32 -> bf16 bits, RNE
    unsigned int u = __float_as_uint(x);
    return (u + 0x7fffu + ((u >> 16) & 1u)) >> 16;
}

__device__ inline void split8(const float4 va, const float4 vb,
                              bf16x8& bh, bf16x8& bl, float& ssq)
{
    float f[8] = {va.x, va.y, va.z, va.w, vb.x, vb.y, vb.z, vb.w};
    unsigned hu[8], lu[8];
    #pragma unroll
    for (int j = 0; j < 8; j++) {
        float x = f[j];
        ssq += x * x;
        unsigned h = f2bf(x);
        float hf = __uint_as_float(h << 16);
        unsigned l = f2bf(x - hf);
        hu[j] = h; lu[j] = l;
    }
    uint4v uh = {hu[0] | (hu[1] << 16), hu[2] | (hu[3] << 16),
                 hu[4] | (hu[5] << 16), hu[6] | (hu[7] << 16)};
    uint4v ul = {lu[0] | (lu[1] << 16), lu[2] | (lu[3] << 16),
                 lu[4] | (lu[5] << 16), lu[6] | (lu[7] << 16)};
    bh = __builtin_bit_cast(bf16x8, uh);
    bl = __builtin_bit_cast(bf16x8, ul);
}

#define MFMA(a, b, c) __builtin_amdgcn_mfma_f32_16x16x32_bf16(a, b, c, 0, 0, 0)

// one-shot grid barrier: ctr zeroed by host-side memsetAsync before launch
__device__ inline void gridbar(unsigned* ctr) {
    __syncthreads();
    __threadfence();   // device-scope release: flush my writes
    if (threadIdx.x == 0) {
        __hip_atomic_fetch_add(ctr, 1u, __ATOMIC_ACQ_REL, __HIP_MEMORY_SCOPE_AGENT);
        while (__hip_atomic_load(ctr, __ATOMIC_ACQUIRE, __HIP_MEMORY_SCOPE_AGENT)
               < (unsigned)NBLK)
            __builtin_amdgcn_s_sleep(2);
    }
    __syncthreads();
    __threadfence();   // acquire side: drop stale cached lines
}

struct SklArgs {
    const float* qe; const float* de; const float* dmask; const float* qmask;
    const float* qidfs; const float* mu; const float* sigma;
    const float* w1; const float* b1; const float* w2; const float* b2;
    const float* w3; const float* b3; const float* dw; const float* chunk;
    float* out;
    ushort* qh; ushort* ql; float* cosm; float* pscore;
    unsigned* ctr;
};

// ---------------------------------------------------------------------------
// Mega-kernel: 4 phases separated by device-scope grid barriers.
// P1 normq (blocks 0..63) -> P2 gemm (752 tiles, stride) ->
// P3 windows (720 tasks, stride) -> P4 topk (blocks 0..7).
// ---------------------------------------------------------------------------
__global__ __launch_bounds__(256) void skl_mega(SklArgs a)
{
    __shared__ float smem[6528];   // 26.1 KB union: gemm red / windows vf+fl / topk s0
    int bid = blockIdx.x;
    int tid = threadIdx.x;
    int wave = tid >> 6, lane = tid & 63;

    // ---------------- Phase 1: normq (normalize + split bf16 hi/lo) --------
    if (bid < 64) {
        int r = bid * 4 + wave;              // 0..255 = b*32+q
        int b = r >> 5, q = r & 31;
        ushort* ph = a.qh + (size_t)r * EE;
        ushort* pl = a.ql + (size_t)r * EE;
        if (q >= QQ) {
            #pragma unroll
            for (int k = 0; k < 3; k++) {
                int e = (lane + 64 * k) * 4;
                *(ushort4*)&ph[e] = make_ushort4(0, 0, 0, 0);
                *(ushort4*)&pl[e] = make_ushort4(0, 0, 0, 0);
            }
        } else {
            const float4* p = (const float4*)(a.qe + (size_t)(b * QQ + q) * EE);
            float4 v[3];
            float ss = 0.f;
            #pragma unroll
            for (int k = 0; k < 3; k++) {
                v[k] = p[lane + 64 * k];
                ss += v[k].x * v[k].x + v[k].y * v[k].y + v[k].z * v[k].z + v[k].w * v[k].w;
            }
            #pragma unroll
            for (int off = 32; off >= 1; off >>= 1) ss += __shfl_xor(ss, off);
            float inv = 1.f / fmaxf(sqrtf(ss), 1e-13f);
            #pragma unroll
            for (int k = 0; k < 3; k++) {
                float f[4] = {v[k].x * inv, v[k].y * inv, v[k].z * inv, v[k].w * inv};
                ushort hs[4], ls[4];
                #pragma unroll
                for (int j = 0; j < 4; j++) {
                    unsigned h = f2bf(f[j]);
                    float hf = __uint_as_float(h << 16);
                    unsigned l = f2bf(f[j] - hf);
                    hs[j] = (ushort)h; ls[j] = (ushort)l;
                }
                int e = (lane + 64 * k) * 4;
                *(ushort4*)&ph[e] = make_ushort4(hs[0], hs[1], hs[2], hs[3]);
                *(ushort4*)&pl[e] = make_ushort4(ls[0], ls[1], ls[2], ls[3]);
            }
        }
    }
    gridbar(a.ctr + 0);

    // ---------------- Phase 2: split-bf16 MFMA GEMM -> final cosine --------
    {
        float (*red)[64][10] = (float (*)[64][10])smem;   // 10.2 KB
        int ln = lane & 15, g = lane >> 4;
        for (int t = bid; t < NT * BB; t += NBLK) {
            int nt = t % NT, b = t / NT;
            int d = nt * 16 + ln;
            int dc = min(d, DD - 1);
            const float* drow = a.de + ((size_t)b * DD + dc) * EE;
            const ushort* qhb = a.qh + (size_t)b * 32 * EE;
            const ushort* qlb = a.ql + (size_t)b * 32 * EE;

            f32x4 acc0 = {0.f, 0.f, 0.f, 0.f};
            f32x4 acc1 = {0.f, 0.f, 0.f, 0.f};
            float ssq = 0.f;
            int k0 = wave * 192;

            #pragma unroll
            for (int kst = 0; kst < 6; kst++) {
                int e0 = k0 + kst * 32 + 8 * g;
                bf16x8 a0h = *(const bf16x8*)&qhb[(size_t)ln * EE + e0];
                bf16x8 a0l = *(const bf16x8*)&qlb[(size_t)ln * EE + e0];
                bf16x8 a1h = *(const bf16x8*)&qhb[(size_t)(16 + ln) * EE + e0];
                bf16x8 a1l = *(const bf16x8*)&qlb[(size_t)(16 + ln) * EE + e0];
                float4 va = *(const float4*)&drow[e0];
                float4 vb = *(const float4*)&drow[e0 + 4];
                bf16x8 bh, bl;
                split8(va, vb, bh, bl, ssq);
                acc0 = MFMA(a0h, bh, acc0);
                acc0 = MFMA(a0h, bl, acc0);
                acc0 = MFMA(a0l, bh, acc0);
                acc1 = MFMA(a1h, bh, acc1);
                acc1 = MFMA(a1h, bl, acc1);
                acc1 = MFMA(a1l, bh, acc1);
            }

            ssq += __shfl_xor(ssq, 16);
            ssq += __shfl_xor(ssq, 32);

            __syncthreads();   // protect red from previous iteration's readers
            #pragma unroll
            for (int j = 0; j < 4; j++) {
                red[wave][lane][j] = acc0[j];
                red[wave][lane][4 + j] = acc1[j];
            }
            red[wave][lane][8] = ssq;
            __syncthreads();

            if (wave == 0) {
                float a0f[4] = {0.f, 0.f, 0.f, 0.f};
                float a1f[4] = {0.f, 0.f, 0.f, 0.f};
                float sf = 0.f;
                #pragma unroll
                for (int w = 0; w < 4; w++) {
                    #pragma unroll
                    for (int j = 0; j < 4; j++) {
                        a0f[j] += red[w][lane][j];
                        a1f[j] += red[w][lane][4 + j];
                    }
                    sf += red[w][lane][8];
                }
                float inv = 1.f / fmaxf(sqrtf(sf), 1e-13f);
                if (d < DD) {
                    #pragma unroll
                    for (int j = 0; j < 4; j++) {
                        int q0 = 4 * g + j;     // C row = 4g+j, col = ln
                        a.cosm[((size_t)b * QQ + q0) * DD + d] = a0f[j] * inv;
                        int q1 = 16 + q0;
                        if (q1 < QQ)
                            a.cosm[((size_t)b * QQ + q1) * DD + d] = a1f[j] * inv;
                    }
                }
            }
        }
    }
    gridbar(a.ctr + 1);

    // ---------------- Phase 3: RBF -> window sums -> saturation ------------
    {
        float (*vf)[DCH] = (float (*)[DCH])smem;     // 11*544 floats
        float* fl = smem + KK * DCH;                 // 544 floats

        float muL[KK], i2s[KK], dwL[KK];
        #pragma unroll
        for (int k = 0; k < KK; k++) {
            muL[k] = a.mu[k];
            float s = a.sigma[k];
            i2s[k] = 1.f / (2.f * s * s);
            dwL[k] = a.dw[k];
        }

        for (int t = bid; t < BB * QQ * 3; t += NBLK) {
            int c  = t % 3;
            int bq = t / 3;
            int b  = bq / QQ;
            int dbase = 512 * c;
            int dcount = min(540, DD - dbase);
            int w = c * 256 + tid;
            bool active = (w < WW);

            const float* dm = a.dmask + (size_t)b * DD + dbase;
            const float* crow = a.cosm + (size_t)bq * DD + dbase;

            __syncthreads();   // protect vf/fl from previous iteration's readers
            for (int i = tid; i < dcount; i += 256) {
                float cc = crow[i];
                float m = dm[i];
                float ssum = 0.f;
                #pragma unroll
                for (int k = 0; k < KK; k++) {
                    float diff = cc - muL[k];
                    float val = __expf(-diff * diff * i2s[k]) * m;
                    ssum += val;
                    vf[k][i] = val;
                }
                fl[i] = (ssum != 0.f) ? 1.f : 0.f;
            }
            __syncthreads();

            if (active) {
                int dl = 2 * tid;
                float pk[KK];
                #pragma unroll
                for (int k = 0; k < KK; k++) pk[k] = 0.f;
                float lenf = 0.f;
                #pragma unroll
                for (int j2 = 0; j2 < WIN / 2; j2++) {
                    float2 f2 = *(const float2*)&fl[dl + 2 * j2];
                    lenf += f2.x + f2.y;
                    #pragma unroll
                    for (int k = 0; k < KK; k++) {
                        float2 v2 = *(const float2*)&vf[k][dl + 2 * j2];
                        pk[k] += v2.x + v2.y;
                    }
                }
                float idf = fmaxf(a.qidfs[bq], 0.f);
                float sat1 = idf * a.w1[0] + lenf * a.w1[1] + a.b1[0];
                float sat2 = 1.f / (idf * a.w2[0] + lenf * a.w2[1] + a.b2[0]);
                float sat3 = idf * a.w3[0] + lenf * a.w3[1] + a.b3[0];
                float mult = a.qmask[bq] * (lenf > 0.f ? 1.f : 0.f);

                float acc = 0.f;
                #pragma unroll
                for (int k = 0; k < KK; k++) {
                    float x = fmaxf(pk[k], 1e-10f);
                    float p = exp2f(sat2 * __log2f(x));
                    acc += (sat1 * p - sat3) * dwL[k];
                }
                a.pscore[(size_t)bq * WW + w] = acc * mult;
            }
        }
    }
    gridbar(a.ctr + 2);

    // ---------------- Phase 4: per-batch top-3 + gather --------------------
    if (bid < BB) {
        float* s0 = smem;     // 736 floats
        int b = bid;

        for (int w = tid; w < WW; w += 256) {
            float s = 0.f;
            for (int q = 0; q < QQ; q++) s += a.pscore[(size_t)(b * QQ + q) * WW + w];
            s0[w] = (s == 0.f) ? -9900.f : s;
        }
        __syncthreads();

        if (tid < 64) {
            float m[12];
            #pragma unroll
            for (int r = 0; r < 12; r++) {
                int w = lane + 64 * r;
                m[r] = (w < WW) ? s0[w] : -3.3e38f;
            }

            int best[3];
            for (int c = 0; c < 3; c++) {
                float bv = -3.3e38f;
                int bi = 1 << 30;
                #pragma unroll
                for (int r = 0; r < 12; r++) {
                    int w = lane + 64 * r;
                    if (w < WW && m[r] > bv) { bv = m[r]; bi = w; }
                }
                #pragma unroll
                for (int off = 32; off >= 1; off >>= 1) {
                    float ov = __shfl_down(bv, off);
                    int oi = __shfl_down(bi, off);
                    if (ov > bv || (ov == bv && oi < bi)) { bv = ov; bi = oi; }
                }
                bi = __shfl(bi, 0);
                best[c] = bi;
                float pen = -10001.f - (float)c;
                #pragma unroll
                for (int r = 0; r < 12; r++) {
                    int w = lane + 64 * r;
                    int dd = w - bi; if (dd < 0) dd = -dd;
                    if (w < WW && dd < 15) m[r] = pen;
                }
            }

            float contrib = 0.f;
            if (lane < 15) {
                int c = lane % 3;
                int g5 = lane / 3;
                const int offs[5] = {0, -1, 1, -2, 2};
                int nb = best[c] + offs[g5];
                nb = min(max(nb, 0), WW - 1);
                float v = s0[nb];
                if (v <= -9900.f) v = 0.f;
                contrib = v * a.chunk[lane];
            }
            #pragma unroll
            for (int off = 32; off >= 1; off >>= 1) contrib += __shfl_down(contrib, off);
            if (lane == 0) a.out[b] = contrib;
        }
    }
}

// ---------------------------------------------------------------------------
extern "C" void kernel_launch(void* const* d_in, const int* in_sizes, int n_in,
                              void* d_out, int out_size, void* d_ws, size_t ws_size,
                              hipStream_t stream) {
    float* ws = (float*)d_ws;
    SklArgs args;
    args.qe    = (const float*)d_in[0];
    args.de    = (const float*)d_in[1];
    args.qmask = (const float*)d_in[2];
    args.dmask = (const float*)d_in[3];
    args.qidfs = (const float*)d_in[4];
    // d_in[5] = document_idfs (unused)
    args.mu    = (const float*)d_in[6];
    args.sigma = (const float*)d_in[7];
    args.w1    = (const float*)d_in[8];
    args.b1    = (const float*)d_in[9];
    args.w2    = (const float*)d_in[10];
    args.b2    = (const float*)d_in[11];
    args.w3    = (const float*)d_in[12];
    args.b3    = (const float*)d_in[13];
    args.dw    = (const float*)d_in[14];
    args.chunk = (const float*)d_in[15];
    args.out   = (float*)d_out;
    args.cosm   = ws;                          // 240*1500 = 360,000 f32
    args.pscore = ws + 360000;                 // 240*736  = 176,640 f32
    args.qh = (ushort*)(ws + 536640);          // 8*32*768 ushort = 98,304 f32 slots
    args.ql = (ushort*)(ws + 536640 + 98304);  // same
    args.ctr = (unsigned*)(ws + 733248);       // 3 barrier counters (zeroed below)

    hipMemsetAsync((void*)args.ctr, 0, 128, stream);
    skl_mega<<<NBLK, 256, 0, stream>>>(args);
}

// Round 14
// 95.944 us; speedup vs baseline: 1.9403x; 1.9403x over previous
//
#include <hip/hip_runtime.h>

// Problem constants (from reference setup_inputs)
#define BB 8
#define QQ 30
#define DD 1500
#define EE 768
#define KK 11
#define WW 736      // (1500-30)/2 + 1
#define WIN 30
#define STR 2

#define NT 94       // n-tiles of 16 d (94*16 = 1504 >= 1500)
#define DCH 544     // windows chunk d-extent (2*255+29+1 = 540, padded)

typedef __attribute__((ext_vector_type(8))) __bf16 bf16x8;
typedef __attribute__((ext_vector_type(4))) float f32x4;
typedef __attribute__((ext_vector_type(4))) unsigned int uint4v;

__device__ inline unsigned int f2bf(float x) {   // f32 -> bf16 bits, RNE
    unsigned int u = __float_as_uint(x);
    return (u + 0x7fffu + ((u >> 16) & 1u)) >> 16;
}

__device__ inline void split8(const float4 va, const float4 vb,
                              bf16x8& bh, bf16x8& bl, float& ssq)
{
    float f[8] = {va.x, va.y, va.z, va.w, vb.x, vb.y, vb.z, vb.w};
    unsigned hu[8], lu[8];
    #pragma unroll
    for (int j = 0; j < 8; j++) {
        float x = f[j];
        ssq += x * x;
        unsigned h = f2bf(x);
        float hf = __uint_as_float(h << 16);
        unsigned l = f2bf(x - hf);
        hu[j] = h; lu[j] = l;
    }
    uint4v uh = {hu[0] | (hu[1] << 16), hu[2] | (hu[3] << 16),
                 hu[4] | (hu[5] << 16), hu[6] | (hu[7] << 16)};
    uint4v ul = {lu[0] | (lu[1] << 16), lu[2] | (lu[3] << 16),
                 lu[4] | (lu[5] << 16), lu[6] | (lu[7] << 16)};
    bh = __builtin_bit_cast(bf16x8, uh);
    bl = __builtin_bit_cast(bf16x8, ul);
}

#define MFMA(a, b, c) __builtin_amdgcn_mfma_f32_16x16x32_bf16(a, b, c, 0, 0, 0)

// ---------------------------------------------------------------------------
// Kernel 1: split-bf16 MFMA GEMM with INLINE normalization (both q and d).
// Block: 16 d x 30 q x K=768; wave w covers K-range [192w, 192w+192).
// Loads raw f32 qe/de, splits to bf16 hi/lo in-registers, accumulates
// q-row and d-row ssq alongside; LDS reduce over 4 waves; writes final
// cosine = dot / (|q||d|).  grid = (94 n-tiles, 8 batches).
// ---------------------------------------------------------------------------
__global__ __launch_bounds__(256) void skl_gemm(
    const float* __restrict__ qe,      // [8][30][768]
    const float* __restrict__ de,      // [8][1500][768]
    float* __restrict__ cosm)          // [8][30][1500] final cosine
{
    __shared__ float red[4][64][12];   // acc0(4) acc1(4) dssq qssq0 qssq1 pad
    __shared__ float qinv[32];
    int tid = threadIdx.x;
    int wave = tid >> 6, lane = tid & 63;
    int ln = lane & 15, g = lane >> 4;
    int nt = blockIdx.x, b = blockIdx.y;
    int d = nt * 16 + ln;
    int dc = min(d, DD - 1);
    const float* drow  = de + ((size_t)b * DD + dc) * EE;
    int r1 = min(16 + ln, QQ - 1);     // clamp: rows 30,31 unused in output
    const float* qrow0 = qe + ((size_t)b * QQ + ln) * EE;
    const float* qrow1 = qe + ((size_t)b * QQ + r1) * EE;

    f32x4 acc0 = {0.f, 0.f, 0.f, 0.f};
    f32x4 acc1 = {0.f, 0.f, 0.f, 0.f};
    float dssq = 0.f, qssq0 = 0.f, qssq1 = 0.f;
    int k0 = wave * 192;

    #pragma unroll
    for (int kst = 0; kst < 6; kst++) {
        int e0 = k0 + kst * 32 + 8 * g;
        bf16x8 a0h, a0l, a1h, a1l, bh, bl;
        {
            float4 va = *(const float4*)&qrow0[e0];
            float4 vb = *(const float4*)&qrow0[e0 + 4];
            split8(va, vb, a0h, a0l, qssq0);
        }
        {
            float4 va = *(const float4*)&qrow1[e0];
            float4 vb = *(const float4*)&qrow1[e0 + 4];
            split8(va, vb, a1h, a1l, qssq1);
        }
        {
            float4 va = *(const float4*)&drow[e0];
            float4 vb = *(const float4*)&drow[e0 + 4];
            split8(va, vb, bh, bl, dssq);
        }
        acc0 = MFMA(a0h, bh, acc0);
        acc0 = MFMA(a0h, bl, acc0);
        acc0 = MFMA(a0l, bh, acc0);
        acc1 = MFMA(a1h, bh, acc1);
        acc1 = MFMA(a1h, bl, acc1);
        acc1 = MFMA(a1l, bh, acc1);
    }

    // reduce ssq over the 4 k-groups (lane bits 4,5) -> per-(row, wave) totals
    dssq  += __shfl_xor(dssq, 16);  dssq  += __shfl_xor(dssq, 32);
    qssq0 += __shfl_xor(qssq0, 16); qssq0 += __shfl_xor(qssq0, 32);
    qssq1 += __shfl_xor(qssq1, 16); qssq1 += __shfl_xor(qssq1, 32);

    #pragma unroll
    for (int j = 0; j < 4; j++) {
        red[wave][lane][j] = acc0[j];
        red[wave][lane][4 + j] = acc1[j];
    }
    red[wave][lane][8] = dssq;
    red[wave][lane][9] = qssq0;
    red[wave][lane][10] = qssq1;
    __syncthreads();

    if (tid < 16) {     // q-row inverse norms (rows tid and 16+tid)
        float q0 = 0.f, q1 = 0.f;
        #pragma unroll
        for (int w = 0; w < 4; w++) {
            q0 += red[w][tid][9];
            q1 += red[w][tid][10];
        }
        qinv[tid]      = 1.f / fmaxf(sqrtf(q0), 1e-13f);
        qinv[16 + tid] = 1.f / fmaxf(sqrtf(q1), 1e-13f);
    }
    __syncthreads();

    if (wave == 0) {
        float a0f[4] = {0.f, 0.f, 0.f, 0.f};
        float a1f[4] = {0.f, 0.f, 0.f, 0.f};
        float sf = 0.f;
        #pragma unroll
        for (int w = 0; w < 4; w++) {
            #pragma unroll
            for (int j = 0; j < 4; j++) {
                a0f[j] += red[w][lane][j];
                a1f[j] += red[w][lane][4 + j];
            }
            sf += red[w][lane][8];
        }
        float dinv = 1.f / fmaxf(sqrtf(sf), 1e-13f);
        if (d < DD) {
            #pragma unroll
            for (int j = 0; j < 4; j++) {
                int q0 = 4 * g + j;     // C row = 4g+j, col = ln
                cosm[((size_t)b * QQ + q0) * DD + d] = a0f[j] * dinv * qinv[q0];
                int q1i = 16 + q0;
                if (q1i < QQ)
                    cosm[((size_t)b * QQ + q1i) * DD + d] = a1f[j] * dinv * qinv[q1i];
            }
        }
    }
}

// ---------------------------------------------------------------------------
// Kernel 2: RBF -> window sums -> saturation -> pscore; the LAST block of
// each batch (device-scope arrival counter) then does q-sum + top-3 + gather.
// Block per (b,q,chunk of 256 windows) = 720 blocks, 90 per batch.
// ---------------------------------------------------------------------------
__global__ __launch_bounds__(256) void skl_windows(
    const float* __restrict__ cosm,    // [8][30][1500]
    const float* __restrict__ dmask,   // [8][1500]
    const float* __restrict__ qmask,   // [8][30]
    const float* __restrict__ qidfs,   // [240]
    const float* __restrict__ mu,      // [11]
    const float* __restrict__ sigma,   // [11]
    const float* __restrict__ w1, const float* __restrict__ b1,
    const float* __restrict__ w2, const float* __restrict__ b2,
    const float* __restrict__ w3, const float* __restrict__ b3,
    const float* __restrict__ dw,      // [11]
    const float* __restrict__ chunk,   // [15]
    float* __restrict__ pscore,        // [240][736]
    unsigned* __restrict__ cnt,        // [8] arrival counters (pre-zeroed)
    float* __restrict__ out)           // [8]
{
    __shared__ float smem[KK * DCH + DCH];   // vf[11][544] + fl[544]; reused as s0
    float (*vf)[DCH] = (float (*)[DCH])smem;
    float* fl = smem + KK * DCH;
    __shared__ int lastFlag;

    int bid = blockIdx.x;     // 0..719
    int c  = bid % 3;
    int bq = bid / 3;         // 0..239
    int b  = bq / QQ;
    int tid = threadIdx.x;

    int dbase = 512 * c;
    int dcount = min(540, DD - dbase);
    int w = c * 256 + tid;
    bool active = (w < WW);

    float muL[KK], i2s[KK], dwL[KK];
    #pragma unroll
    for (int k = 0; k < KK; k++) {
        muL[k] = mu[k];
        float s = sigma[k];
        i2s[k] = 1.f / (2.f * s * s);
        dwL[k] = dw[k];
    }
    const float* dm = dmask + (size_t)b * DD + dbase;
    const float* crow = cosm + (size_t)bq * DD + dbase;

    // phase 1: 11 RBF values per d
    for (int i = tid; i < dcount; i += 256) {
        float cc = crow[i];
        float m = dm[i];
        float ssum = 0.f;
        #pragma unroll
        for (int k = 0; k < KK; k++) {
            float diff = cc - muL[k];
            float val = __expf(-diff * diff * i2s[k]) * m;
            ssum += val;
            vf[k][i] = val;
        }
        fl[i] = (ssum != 0.f) ? 1.f : 0.f;
    }
    __syncthreads();

    // phase 2: per-window sums + saturation + dense_w
    if (active) {
        int dl = 2 * tid;
        float pk[KK];
        #pragma unroll
        for (int k = 0; k < KK; k++) pk[k] = 0.f;
        float lenf = 0.f;
        #pragma unroll
        for (int j2 = 0; j2 < WIN / 2; j2++) {
            float2 f2 = *(const float2*)&fl[dl + 2 * j2];
            lenf += f2.x + f2.y;
            #pragma unroll
            for (int k = 0; k < KK; k++) {
                float2 v2 = *(const float2*)&vf[k][dl + 2 * j2];
                pk[k] += v2.x + v2.y;
            }
        }
        float idf = fmaxf(qidfs[bq], 0.f);
        float sat1 = idf * w1[0] + lenf * w1[1] + b1[0];
        float sat2 = 1.f / (idf * w2[0] + lenf * w2[1] + b2[0]);
        float sat3 = idf * w3[0] + lenf * w3[1] + b3[0];
        float mult = qmask[bq] * (lenf > 0.f ? 1.f : 0.f);

        float acc = 0.f;
        #pragma unroll
        for (int k = 0; k < KK; k++) {
            float x = fmaxf(pk[k], 1e-10f);
            float p = exp2f(sat2 * __log2f(x));
            acc += (sat1 * p - sat3) * dwL[k];
        }
        pscore[(size_t)bq * WW + w] = acc * mult;
    }

    // ---- last-arrival: the 90th block of batch b does q-sum + topk --------
    __syncthreads();
    __threadfence();   // release pscore writes
    if (tid == 0) {
        unsigned old = __hip_atomic_fetch_add(&cnt[b], 1u, __ATOMIC_ACQ_REL,
                                              __HIP_MEMORY_SCOPE_AGENT);
        lastFlag = (old == (unsigned)(QQ * 3 - 1)) ? 1 : 0;
    }
    __syncthreads();
    if (!lastFlag) return;
    __threadfence();   // acquire: see all 90 blocks' pscore writes

    float* s0 = smem;  // reuse LDS (736 floats)
    for (int ww = tid; ww < WW; ww += 256) {
        float s = 0.f;
        for (int q = 0; q < QQ; q++) s += pscore[(size_t)(b * QQ + q) * WW + ww];
        s0[ww] = (s == 0.f) ? -9900.f : s;
    }
    __syncthreads();

    if (tid < 64) {
        int lane = tid;
        float m[12];
        #pragma unroll
        for (int r = 0; r < 12; r++) {
            int ww = lane + 64 * r;
            m[r] = (ww < WW) ? s0[ww] : -3.3e38f;
        }

        int best[3];
        for (int cc2 = 0; cc2 < 3; cc2++) {
            float bv = -3.3e38f;
            int bi = 1 << 30;
            #pragma unroll
            for (int r = 0; r < 12; r++) {
                int ww = lane + 64 * r;
                if (ww < WW && m[r] > bv) { bv = m[r]; bi = ww; }
            }
            #pragma unroll
            for (int off = 32; off >= 1; off >>= 1) {
                float ov = __shfl_down(bv, off);
                int oi = __shfl_down(bi, off);
                if (ov > bv || (ov == bv && oi < bi)) { bv = ov; bi = oi; }
            }
            bi = __shfl(bi, 0);
            best[cc2] = bi;
            float pen = -10001.f - (float)cc2;
            #pragma unroll
            for (int r = 0; r < 12; r++) {
                int ww = lane + 64 * r;
                int dd = ww - bi; if (dd < 0) dd = -dd;
                if (ww < WW && dd < 15) m[r] = pen;
            }
        }

        float contrib = 0.f;
        if (lane < 15) {
            int cc2 = lane % 3;
            int g5 = lane / 3;
            const int offs[5] = {0, -1, 1, -2, 2};
            int nb = best[cc2] + offs[g5];
            nb = min(max(nb, 0), WW - 1);
            float v = s0[nb];
            if (v <= -9900.f) v = 0.f;
            contrib = v * chunk[lane];
        }
        #pragma unroll
        for (int off = 32; off >= 1; off >>= 1) contrib += __shfl_down(contrib, off);
        if (lane == 0) out[b] = contrib;
    }
}

// ---------------------------------------------------------------------------
extern "C" void kernel_launch(void* const* d_in, const int* in_sizes, int n_in,
                              void* d_out, int out_size, void* d_ws, size_t ws_size,
                              hipStream_t stream) {
    const float* qe    = (const float*)d_in[0];   // (8,30,768)
    const float* de    = (const float*)d_in[1];   // (8,1500,768)
    const float* qmask = (const float*)d_in[2];   // (8,30)
    const float* dmask = (const float*)d_in[3];   // (8,1500)
    const float* qidfs = (const float*)d_in[4];   // (8,30,1)
    // d_in[5] = document_idfs (unused)
    const float* mu    = (const float*)d_in[6];   // (11,)
    const float* sigma = (const float*)d_in[7];   // (11,)
    const float* w1    = (const float*)d_in[8];
    const float* b1    = (const float*)d_in[9];
    const float* w2    = (const float*)d_in[10];
    const float* b2    = (const float*)d_in[11];
    const float* w3    = (const float*)d_in[12];
    const float* b3    = (const float*)d_in[13];
    const float* dw    = (const float*)d_in[14];  // (1,11)
    const float* chunk = (const float*)d_in[15];  // (1,15)
    float* out = (float*)d_out;

    float* ws = (float*)d_ws;
    float* cosm   = ws;                      // 240*1500 = 360,000 f32
    float* pscore = ws + 360000;             // 240*736  = 176,640 f32
    unsigned* cnt = (unsigned*)(ws + 536640);// 8 arrival counters

    hipMemsetAsync((void*)cnt, 0, 128, stream);
    skl_gemm<<<dim3(NT, BB), 256, 0, stream>>>(qe, de, cosm);
    skl_windows<<<BB * QQ * 3, 256, 0, stream>>>(cosm, dmask, qmask, qidfs,
                                                 mu, sigma, w1, b1, w2, b2, w3, b3,
                                                 dw, chunk, pscore, cnt, out);
}

// Round 15
// 37.478 us; speedup vs baseline: 4.9673x; 2.5600x over previous
//
#include <hip/hip_runtime.h>

// Problem constants (from reference setup_inputs)
#define BB 8
#define QQ 30
#define DD 1500
#define EE 768
#define KK 11
#define WW 736      // (1500-30)/2 + 1
#define WIN 30
#define STR 2

#define NT 94       // n-tiles of 16 d (94*16 = 1504 >= 1500)
#define DCH 544     // windows chunk d-extent (2*255+29+1 = 540, padded)

typedef __attribute__((ext_vector_type(8))) __bf16 bf16x8;
typedef __attribute__((ext_vector_type(4))) float f32x4;
typedef __attribute__((ext_vector_type(4))) unsigned int uint4v;

__device__ inline unsigned int f2bf(float x) {   // f32 -> bf16 bits, RNE
    unsigned int u = __float_as_uint(x);
    return (u + 0x7fffu + ((u >> 16) & 1u)) >> 16;
}

__device__ inline void split8(const float4 va, const float4 vb,
                              bf16x8& bh, bf16x8& bl, float& ssq)
{
    float f[8] = {va.x, va.y, va.z, va.w, vb.x, vb.y, vb.z, vb.w};
    unsigned hu[8], lu[8];
    #pragma unroll
    for (int j = 0; j < 8; j++) {
        float x = f[j];
        ssq += x * x;
        unsigned h = f2bf(x);
        float hf = __uint_as_float(h << 16);
        unsigned l = f2bf(x - hf);
        hu[j] = h; lu[j] = l;
    }
    uint4v uh = {hu[0] | (hu[1] << 16), hu[2] | (hu[3] << 16),
                 hu[4] | (hu[5] << 16), hu[6] | (hu[7] << 16)};
    uint4v ul = {lu[0] | (lu[1] << 16), lu[2] | (lu[3] << 16),
                 lu[4] | (lu[5] << 16), lu[6] | (lu[7] << 16)};
    bh = __builtin_bit_cast(bf16x8, uh);
    bl = __builtin_bit_cast(bf16x8, ul);
}

#define MFMA(a, b, c) __builtin_amdgcn_mfma_f32_16x16x32_bf16(a, b, c, 0, 0, 0)

// ---------------------------------------------------------------------------
// Kernel 1: split-bf16 MFMA GEMM with INLINE normalization (both q and d).
// Block: 16 d x 30 q x K=768; wave w covers K-range [192w, 192w+192).
// Loads raw f32 qe/de, splits to bf16 hi/lo in-registers, accumulates
// q-row and d-row ssq alongside; LDS reduce over 4 waves; writes final
// cosine = dot / (|q||d|).  grid = (94 n-tiles, 8 batches).
// ---------------------------------------------------------------------------
__global__ __launch_bounds__(256) void skl_gemm(
    const float* __restrict__ qe,      // [8][30][768]
    const float* __restrict__ de,      // [8][1500][768]
    float* __restrict__ cosm)          // [8][30][1500] final cosine
{
    __shared__ float red[4][64][12];   // acc0(4) acc1(4) dssq qssq0 qssq1 pad
    __shared__ float qinv[32];
    int tid = threadIdx.x;
    int wave = tid >> 6, lane = tid & 63;
    int ln = lane & 15, g = lane >> 4;
    int nt = blockIdx.x, b = blockIdx.y;
    int d = nt * 16 + ln;
    int dc = min(d, DD - 1);
    const float* drow  = de + ((size_t)b * DD + dc) * EE;
    int r1 = min(16 + ln, QQ - 1);     // clamp: rows 30,31 unused in output
    const float* qrow0 = qe + ((size_t)b * QQ + ln) * EE;
    const float* qrow1 = qe + ((size_t)b * QQ + r1) * EE;

    f32x4 acc0 = {0.f, 0.f, 0.f, 0.f};
    f32x4 acc1 = {0.f, 0.f, 0.f, 0.f};
    float dssq = 0.f, qssq0 = 0.f, qssq1 = 0.f;
    int k0 = wave * 192;

    #pragma unroll
    for (int kst = 0; kst < 6; kst++) {
        int e0 = k0 + kst * 32 + 8 * g;
        bf16x8 a0h, a0l, a1h, a1l, bh, bl;
        {
            float4 va = *(const float4*)&qrow0[e0];
            float4 vb = *(const float4*)&qrow0[e0 + 4];
            split8(va, vb, a0h, a0l, qssq0);
        }
        {
            float4 va = *(const float4*)&qrow1[e0];
            float4 vb = *(const float4*)&qrow1[e0 + 4];
            split8(va, vb, a1h, a1l, qssq1);
        }
        {
            float4 va = *(const float4*)&drow[e0];
            float4 vb = *(const float4*)&drow[e0 + 4];
            split8(va, vb, bh, bl, dssq);
        }
        acc0 = MFMA(a0h, bh, acc0);
        acc0 = MFMA(a0h, bl, acc0);
        acc0 = MFMA(a0l, bh, acc0);
        acc1 = MFMA(a1h, bh, acc1);
        acc1 = MFMA(a1h, bl, acc1);
        acc1 = MFMA(a1l, bh, acc1);
    }

    // reduce ssq over the 4 k-groups (lane bits 4,5) -> per-(row, wave) totals
    dssq  += __shfl_xor(dssq, 16);  dssq  += __shfl_xor(dssq, 32);
    qssq0 += __shfl_xor(qssq0, 16); qssq0 += __shfl_xor(qssq0, 32);
    qssq1 += __shfl_xor(qssq1, 16); qssq1 += __shfl_xor(qssq1, 32);

    #pragma unroll
    for (int j = 0; j < 4; j++) {
        red[wave][lane][j] = acc0[j];
        red[wave][lane][4 + j] = acc1[j];
    }
    red[wave][lane][8] = dssq;
    red[wave][lane][9] = qssq0;
    red[wave][lane][10] = qssq1;
    __syncthreads();

    if (tid < 16) {     // q-row inverse norms (rows tid and 16+tid)
        float q0 = 0.f, q1 = 0.f;
        #pragma unroll
        for (int w = 0; w < 4; w++) {
            q0 += red[w][tid][9];
            q1 += red[w][tid][10];
        }
        qinv[tid]      = 1.f / fmaxf(sqrtf(q0), 1e-13f);
        qinv[16 + tid] = 1.f / fmaxf(sqrtf(q1), 1e-13f);
    }
    __syncthreads();

    if (wave == 0) {
        float a0f[4] = {0.f, 0.f, 0.f, 0.f};
        float a1f[4] = {0.f, 0.f, 0.f, 0.f};
        float sf = 0.f;
        #pragma unroll
        for (int w = 0; w < 4; w++) {
            #pragma unroll
            for (int j = 0; j < 4; j++) {
                a0f[j] += red[w][lane][j];
                a1f[j] += red[w][lane][4 + j];
            }
            sf += red[w][lane][8];
        }
        float dinv = 1.f / fmaxf(sqrtf(sf), 1e-13f);
        if (d < DD) {
            #pragma unroll
            for (int j = 0; j < 4; j++) {
                int q0 = 4 * g + j;     // C row = 4g+j, col = ln
                cosm[((size_t)b * QQ + q0) * DD + d] = a0f[j] * dinv * qinv[q0];
                int q1i = 16 + q0;
                if (q1i < QQ)
                    cosm[((size_t)b * QQ + q1i) * DD + d] = a1f[j] * dinv * qinv[q1i];
            }
        }
    }
}

// ---------------------------------------------------------------------------
// Kernel 2: RBF (f32 __expf) -> window sums -> saturation -> pscore.
// Block per (b,q,chunk of 256 windows) = 720 blocks. No sync primitives.
// ---------------------------------------------------------------------------
__global__ __launch_bounds__(256) void skl_windows(
    const float* __restrict__ cosm,    // [8][30][1500]
    const float* __restrict__ dmask,   // [8][1500]
    const float* __restrict__ qmask,   // [8][30]
    const float* __restrict__ qidfs,   // [240]
    const float* __restrict__ mu,      // [11]
    const float* __restrict__ sigma,   // [11]
    const float* __restrict__ w1, const float* __restrict__ b1,
    const float* __restrict__ w2, const float* __restrict__ b2,
    const float* __restrict__ w3, const float* __restrict__ b3,
    const float* __restrict__ dw,      // [11]
    float* __restrict__ pscore)        // [240][736]
{
    __shared__ float vf[KK][DCH];      // 23.9 KB
    __shared__ float fl[DCH];          // 2.2 KB

    int bid = blockIdx.x;     // 0..719
    int c  = bid % 3;
    int bq = bid / 3;         // 0..239
    int b  = bq / QQ;
    int tid = threadIdx.x;

    int dbase = 512 * c;
    int dcount = min(540, DD - dbase);
    int w = c * 256 + tid;
    bool active = (w < WW);

    float muL[KK], i2s[KK], dwL[KK];
    #pragma unroll
    for (int k = 0; k < KK; k++) {
        muL[k] = mu[k];
        float s = sigma[k];
        i2s[k] = 1.f / (2.f * s * s);
        dwL[k] = dw[k];
    }
    const float* dm = dmask + (size_t)b * DD + dbase;
    const float* crow = cosm + (size_t)bq * DD + dbase;

    // phase 1: 11 RBF values per d
    for (int i = tid; i < dcount; i += 256) {
        float cc = crow[i];
        float m = dm[i];
        float ssum = 0.f;
        #pragma unroll
        for (int k = 0; k < KK; k++) {
            float diff = cc - muL[k];
            float val = __expf(-diff * diff * i2s[k]) * m;
            ssum += val;
            vf[k][i] = val;
        }
        fl[i] = (ssum != 0.f) ? 1.f : 0.f;
    }
    __syncthreads();

    // phase 2: per-window sums + saturation + dense_w
    if (active) {
        int dl = 2 * tid;
        float pk[KK];
        #pragma unroll
        for (int k = 0; k < KK; k++) pk[k] = 0.f;
        float lenf = 0.f;
        #pragma unroll
        for (int j2 = 0; j2 < WIN / 2; j2++) {
            float2 f2 = *(const float2*)&fl[dl + 2 * j2];
            lenf += f2.x + f2.y;
            #pragma unroll
            for (int k = 0; k < KK; k++) {
                float2 v2 = *(const float2*)&vf[k][dl + 2 * j2];
                pk[k] += v2.x + v2.y;
            }
        }
        float idf = fmaxf(qidfs[bq], 0.f);
        float sat1 = idf * w1[0] + lenf * w1[1] + b1[0];
        float sat2 = 1.f / (idf * w2[0] + lenf * w2[1] + b2[0]);
        float sat3 = idf * w3[0] + lenf * w3[1] + b3[0];
        float mult = qmask[bq] * (lenf > 0.f ? 1.f : 0.f);

        float acc = 0.f;
        #pragma unroll
        for (int k = 0; k < KK; k++) {
            float x = fmaxf(pk[k], 1e-10f);
            float p = exp2f(sat2 * __log2f(x));
            acc += (sat1 * p - sat3) * dwL[k];
        }
        pscore[(size_t)bq * WW + w] = acc * mult;
    }
}

// ---------------------------------------------------------------------------
// Kernel 3: per batch: sum over q (256 threads), then single-wave top-3
// argmax + pooling + gather.
// ---------------------------------------------------------------------------
__global__ __launch_bounds__(256) void skl_topk(
    const float* __restrict__ pscore,  // [240][736]
    const float* __restrict__ chunk,   // [15]
    float* __restrict__ out)           // [8]
{
    __shared__ float s0[WW];
    int b = blockIdx.x;
    int tid = threadIdx.x;

    for (int w = tid; w < WW; w += 256) {
        float s = 0.f;
        for (int q = 0; q < QQ; q++) s += pscore[(size_t)(b * QQ + q) * WW + w];
        s0[w] = (s == 0.f) ? -9900.f : s;
    }
    __syncthreads();

    if (tid < 64) {
        int lane = tid;
        float m[12];
        #pragma unroll
        for (int r = 0; r < 12; r++) {
            int w = lane + 64 * r;
            m[r] = (w < WW) ? s0[w] : -3.3e38f;
        }

        int best[3];
        for (int c = 0; c < 3; c++) {
            float bv = -3.3e38f;
            int bi = 1 << 30;
            #pragma unroll
            for (int r = 0; r < 12; r++) {
                int w = lane + 64 * r;
                if (w < WW && m[r] > bv) { bv = m[r]; bi = w; }
            }
            #pragma unroll
            for (int off = 32; off >= 1; off >>= 1) {
                float ov = __shfl_down(bv, off);
                int oi = __shfl_down(bi, off);
                if (ov > bv || (ov == bv && oi < bi)) { bv = ov; bi = oi; }
            }
            bi = __shfl(bi, 0);
            best[c] = bi;
            float pen = -10001.f - (float)c;
            #pragma unroll
            for (int r = 0; r < 12; r++) {
                int w = lane + 64 * r;
                int dd = w - bi; if (dd < 0) dd = -dd;
                if (w < WW && dd < 15) m[r] = pen;
            }
        }

        float contrib = 0.f;
        if (lane < 15) {
            int c = lane % 3;
            int g = lane / 3;
            const int offs[5] = {0, -1, 1, -2, 2};
            int nb = best[c] + offs[g];
            nb = min(max(nb, 0), WW - 1);
            float v = s0[nb];
            if (v <= -9900.f) v = 0.f;
            contrib = v * chunk[lane];
        }
        #pragma unroll
        for (int off = 32; off >= 1; off >>= 1) contrib += __shfl_down(contrib, off);
        if (lane == 0) out[b] = contrib;
    }
}

// ---------------------------------------------------------------------------
extern "C" void kernel_launch(void* const* d_in, const int* in_sizes, int n_in,
                              void* d_out, int out_size, void* d_ws, size_t ws_size,
                              hipStream_t stream) {
    const float* qe    = (const float*)d_in[0];   // (8,30,768)
    const float* de    = (const float*)d_in[1];   // (8,1500,768)
    const float* qmask = (const float*)d_in[2];   // (8,30)
    const float* dmask = (const float*)d_in[3];   // (8,1500)
    const float* qidfs = (const float*)d_in[4];   // (8,30,1)
    // d_in[5] = document_idfs (unused)
    const float* mu    = (const float*)d_in[6];   // (11,)
    const float* sigma = (const float*)d_in[7];   // (11,)
    const float* w1    = (const float*)d_in[8];
    const float* b1    = (const float*)d_in[9];
    const float* w2    = (const float*)d_in[10];
    const float* b2    = (const float*)d_in[11];
    const float* w3    = (const float*)d_in[12];
    const float* b3    = (const float*)d_in[13];
    const float* dw    = (const float*)d_in[14];  // (1,11)
    const float* chunk = (const float*)d_in[15];  // (1,15)
    float* out = (float*)d_out;

    float* ws = (float*)d_ws;
    float* cosm   = ws;                      // 240*1500 = 360,000 f32
    float* pscore = ws + 360000;             // 240*736  = 176,640 f32  (~2.1MB)

    skl_gemm<<<dim3(NT, BB), 256, 0, stream>>>(qe, de, cosm);
    skl_windows<<<BB * QQ * 3, 256, 0, stream>>>(cosm, dmask, qmask, qidfs,
                                                 mu, sigma, w1, b1, w2, b2, w3, b3,
                                                 dw, pscore);
    skl_topk<<<BB, 256, 0, stream>>>(pscore, chunk, out);
}

// Round 16
// 34.039 us; speedup vs baseline: 5.4692x; 1.1010x over previous
//
#include <hip/hip_runtime.h>

// Problem constants (from reference setup_inputs)
#define BB 8
#define QQ 30
#define DD 1500
#define EE 768
#define KK 11
#define WW 736      // (1500-30)/2 + 1
#define WIN 30
#define STR 2

#define NT 94       // n-tiles of 16 d (94*16 = 1504 >= 1500)
#define DCH 544     // windows chunk d-extent (2*255+29+1 = 540, padded)

typedef __attribute__((ext_vector_type(8))) __bf16 bf16x8;
typedef __attribute__((ext_vector_type(4))) float f32x4;
typedef __attribute__((ext_vector_type(4))) unsigned int uint4v;

// ---------------------------------------------------------------------------
// truncation split: x = hi + lo + O(2^-16 x); hi = bf16-trunc(x) (bit mask,
// no shift needed for the f32 value), lo = bf16-trunc(x - hi).
// Dropped terms in a*b: lo_a*lo_b + trunc residuals ~ 3*2^-16 |ab| -- cos
// abs error ~2e-6, ~250x below the argmax-flip scale established in R1.
// ~48 VALU per 8 elems (vs ~120 for the RNE version).
// ---------------------------------------------------------------------------
__device__ inline void split8(const float4 va, const float4 vb,
                              bf16x8& bh, bf16x8& bl, float& ssq)
{
    float f[8] = {va.x, va.y, va.z, va.w, vb.x, vb.y, vb.z, vb.w};
    unsigned hu[8];
    float r[8];
    #pragma unroll
    for (int j = 0; j < 8; j++) {
        float x = f[j];
        ssq += x * x;
        unsigned hb = __float_as_uint(x) & 0xffff0000u;
        hu[j] = hb;
        r[j] = x - __uint_as_float(hb);
    }
    uint4v uh, ul;
    #pragma unroll
    for (int j = 0; j < 4; j++) {
        uh[j] = hu[2 * j + 1] | (hu[2 * j] >> 16);
        unsigned l0 = __float_as_uint(r[2 * j]) >> 16;
        unsigned l1 = __float_as_uint(r[2 * j + 1]) & 0xffff0000u;
        ul[j] = l1 | l0;
    }
    bh = __builtin_bit_cast(bf16x8, uh);
    bl = __builtin_bit_cast(bf16x8, ul);
}

#define MFMA(a, b, c) __builtin_amdgcn_mfma_f32_16x16x32_bf16(a, b, c, 0, 0, 0)

// ---------------------------------------------------------------------------
// Kernel 1: split-bf16 MFMA GEMM with INLINE normalization (both q and d).
// Block: 16 d x 30 q x K=768; wave w covers K-range [192w, 192w+192).
// Loads raw f32 qe/de, truncation-splits to bf16 hi/lo in-registers,
// accumulates q-row and d-row ssq alongside; LDS reduce over 4 waves;
// writes final cosine = dot / (|q||d|).  grid = (94 n-tiles, 8 batches).
// ---------------------------------------------------------------------------
__global__ __launch_bounds__(256) void skl_gemm(
    const float* __restrict__ qe,      // [8][30][768]
    const float* __restrict__ de,      // [8][1500][768]
    float* __restrict__ cosm)          // [8][30][1500] final cosine
{
    __shared__ float red[4][64][12];   // acc0(4) acc1(4) dssq qssq0 qssq1 pad
    __shared__ float qinv[32];
    int tid = threadIdx.x;
    int wave = tid >> 6, lane = tid & 63;
    int ln = lane & 15, g = lane >> 4;
    int nt = blockIdx.x, b = blockIdx.y;
    int d = nt * 16 + ln;
    int dc = min(d, DD - 1);
    const float* drow  = de + ((size_t)b * DD + dc) * EE;
    int r1 = min(16 + ln, QQ - 1);     // clamp: rows 30,31 unused in output
    const float* qrow0 = qe + ((size_t)b * QQ + ln) * EE;
    const float* qrow1 = qe + ((size_t)b * QQ + r1) * EE;

    f32x4 acc0 = {0.f, 0.f, 0.f, 0.f};
    f32x4 acc1 = {0.f, 0.f, 0.f, 0.f};
    float dssq = 0.f, qssq0 = 0.f, qssq1 = 0.f;
    int k0 = wave * 192;

    #pragma unroll
    for (int kst = 0; kst < 6; kst++) {
        int e0 = k0 + kst * 32 + 8 * g;
        bf16x8 a0h, a0l, a1h, a1l, bh, bl;
        {
            float4 va = *(const float4*)&qrow0[e0];
            float4 vb = *(const float4*)&qrow0[e0 + 4];
            split8(va, vb, a0h, a0l, qssq0);
        }
        {
            float4 va = *(const float4*)&qrow1[e0];
            float4 vb = *(const float4*)&qrow1[e0 + 4];
            split8(va, vb, a1h, a1l, qssq1);
        }
        {
            float4 va = *(const float4*)&drow[e0];
            float4 vb = *(const float4*)&drow[e0 + 4];
            split8(va, vb, bh, bl, dssq);
        }
        acc0 = MFMA(a0h, bh, acc0);
        acc0 = MFMA(a0h, bl, acc0);
        acc0 = MFMA(a0l, bh, acc0);
        acc1 = MFMA(a1h, bh, acc1);
        acc1 = MFMA(a1h, bl, acc1);
        acc1 = MFMA(a1l, bh, acc1);
    }

    // reduce ssq over the 4 k-groups (lane bits 4,5) -> per-(row, wave) totals
    dssq  += __shfl_xor(dssq, 16);  dssq  += __shfl_xor(dssq, 32);
    qssq0 += __shfl_xor(qssq0, 16); qssq0 += __shfl_xor(qssq0, 32);
    qssq1 += __shfl_xor(qssq1, 16); qssq1 += __shfl_xor(qssq1, 32);

    #pragma unroll
    for (int j = 0; j < 4; j++) {
        red[wave][lane][j] = acc0[j];
        red[wave][lane][4 + j] = acc1[j];
    }
    red[wave][lane][8] = dssq;
    red[wave][lane][9] = qssq0;
    red[wave][lane][10] = qssq1;
    __syncthreads();

    if (tid < 16) {     // q-row inverse norms (rows tid and 16+tid)
        float q0 = 0.f, q1 = 0.f;
        #pragma unroll
        for (int w = 0; w < 4; w++) {
            q0 += red[w][tid][9];
            q1 += red[w][tid][10];
        }
        qinv[tid]      = 1.f / fmaxf(sqrtf(q0), 1e-13f);
        qinv[16 + tid] = 1.f / fmaxf(sqrtf(q1), 1e-13f);
    }
    __syncthreads();

    if (wave == 0) {
        float a0f[4] = {0.f, 0.f, 0.f, 0.f};
        float a1f[4] = {0.f, 0.f, 0.f, 0.f};
        float sf = 0.f;
        #pragma unroll
        for (int w = 0; w < 4; w++) {
            #pragma unroll
            for (int j = 0; j < 4; j++) {
                a0f[j] += red[w][lane][j];
                a1f[j] += red[w][lane][4 + j];
            }
            sf += red[w][lane][8];
        }
        float dinv = 1.f / fmaxf(sqrtf(sf), 1e-13f);
        if (d < DD) {
            #pragma unroll
            for (int j = 0; j < 4; j++) {
                int q0 = 4 * g + j;     // C row = 4g+j, col = ln
                cosm[((size_t)b * QQ + q0) * DD + d] = a0f[j] * dinv * qinv[q0];
                int q1i = 16 + q0;
                if (q1i < QQ)
                    cosm[((size_t)b * QQ + q1i) * DD + d] = a1f[j] * dinv * qinv[q1i];
            }
        }
    }
}

// ---------------------------------------------------------------------------
// Kernel 2: RBF (f32 __expf) -> window sums -> saturation -> pscore.
// Block per (b,q,chunk of 256 windows) = 720 blocks. No sync primitives.
// ---------------------------------------------------------------------------
__global__ __launch_bounds__(256) void skl_windows(
    const float* __restrict__ cosm,    // [8][30][1500]
    const float* __restrict__ dmask,   // [8][1500]
    const float* __restrict__ qmask,   // [8][30]
    const float* __restrict__ qidfs,   // [240]
    const float* __restrict__ mu,      // [11]
    const float* __restrict__ sigma,   // [11]
    const float* __restrict__ w1, const float* __restrict__ b1,
    const float* __restrict__ w2, const float* __restrict__ b2,
    const float* __restrict__ w3, const float* __restrict__ b3,
    const float* __restrict__ dw,      // [11]
    float* __restrict__ pscore)        // [240][736]
{
    __shared__ float vf[KK][DCH];      // 23.9 KB
    __shared__ float fl[DCH];          // 2.2 KB

    int bid = blockIdx.x;     // 0..719
    int c  = bid % 3;
    int bq = bid / 3;         // 0..239
    int b  = bq / QQ;
    int tid = threadIdx.x;

    int dbase = 512 * c;
    int dcount = min(540, DD - dbase);
    int w = c * 256 + tid;
    bool active = (w < WW);

    float muL[KK], i2s[KK], dwL[KK];
    #pragma unroll
    for (int k = 0; k < KK; k++) {
        muL[k] = mu[k];
        float s = sigma[k];
        i2s[k] = 1.f / (2.f * s * s);
        dwL[k] = dw[k];
    }
    const float* dm = dmask + (size_t)b * DD + dbase;
    const float* crow = cosm + (size_t)bq * DD + dbase;

    // phase 1: 11 RBF values per d
    for (int i = tid; i < dcount; i += 256) {
        float cc = crow[i];
        float m = dm[i];
        float ssum = 0.f;
        #pragma unroll
        for (int k = 0; k < KK; k++) {
            float diff = cc - muL[k];
            float val = __expf(-diff * diff * i2s[k]) * m;
            ssum += val;
            vf[k][i] = val;
        }
        fl[i] = (ssum != 0.f) ? 1.f : 0.f;
    }
    __syncthreads();

    // phase 2: per-window sums + saturation + dense_w
    if (active) {
        int dl = 2 * tid;
        float pk[KK];
        #pragma unroll
        for (int k = 0; k < KK; k++) pk[k] = 0.f;
        float lenf = 0.f;
        #pragma unroll
        for (int j2 = 0; j2 < WIN / 2; j2++) {
            float2 f2 = *(const float2*)&fl[dl + 2 * j2];
            lenf += f2.x + f2.y;
            #pragma unroll
            for (int k = 0; k < KK; k++) {
                float2 v2 = *(const float2*)&vf[k][dl + 2 * j2];
                pk[k] += v2.x + v2.y;
            }
        }
        float idf = fmaxf(qidfs[bq], 0.f);
        float sat1 = idf * w1[0] + lenf * w1[1] + b1[0];
        float sat2 = 1.f / (idf * w2[0] + lenf * w2[1] + b2[0]);
        float sat3 = idf * w3[0] + lenf * w3[1] + b3[0];
        float mult = qmask[bq] * (lenf > 0.f ? 1.f : 0.f);

        float acc = 0.f;
        #pragma unroll
        for (int k = 0; k < KK; k++) {
            float x = fmaxf(pk[k], 1e-10f);
            float p = exp2f(sat2 * __log2f(x));
            acc += (sat1 * p - sat3) * dwL[k];
        }
        pscore[(size_t)bq * WW + w] = acc * mult;
    }
}

// ---------------------------------------------------------------------------
// Kernel 3: per batch: sum over q (float4-vectorized), then single-wave
// top-3 argmax + pooling + gather.
// ---------------------------------------------------------------------------
__global__ __launch_bounds__(256) void skl_topk(
    const float* __restrict__ pscore,  // [240][736]
    const float* __restrict__ chunk,   // [15]
    float* __restrict__ out)           // [8]
{
    __shared__ float s0[WW];
    int b = blockIdx.x;
    int tid = threadIdx.x;

    if (tid < WW / 4) {                // 184 threads, one float4 of w each
        float4 s = make_float4(0.f, 0.f, 0.f, 0.f);
        for (int q = 0; q < QQ; q++) {
            float4 v = *(const float4*)&pscore[(size_t)(b * QQ + q) * WW + 4 * tid];
            s.x += v.x; s.y += v.y; s.z += v.z; s.w += v.w;
        }
        s0[4 * tid + 0] = (s.x == 0.f) ? -9900.f : s.x;
        s0[4 * tid + 1] = (s.y == 0.f) ? -9900.f : s.y;
        s0[4 * tid + 2] = (s.z == 0.f) ? -9900.f : s.z;
        s0[4 * tid + 3] = (s.w == 0.f) ? -9900.f : s.w;
    }
    __syncthreads();

    if (tid < 64) {
        int lane = tid;
        float m[12];
        #pragma unroll
        for (int r = 0; r < 12; r++) {
            int w = lane + 64 * r;
            m[r] = (w < WW) ? s0[w] : -3.3e38f;
        }

        int best[3];
        for (int c = 0; c < 3; c++) {
            float bv = -3.3e38f;
            int bi = 1 << 30;
            #pragma unroll
            for (int r = 0; r < 12; r++) {
                int w = lane + 64 * r;
                if (w < WW && m[r] > bv) { bv = m[r]; bi = w; }
            }
            #pragma unroll
            for (int off = 32; off >= 1; off >>= 1) {
                float ov = __shfl_down(bv, off);
                int oi = __shfl_down(bi, off);
                if (ov > bv || (ov == bv && oi < bi)) { bv = ov; bi = oi; }
            }
            bi = __shfl(bi, 0);
            best[c] = bi;
            float pen = -10001.f - (float)c;
            #pragma unroll
            for (int r = 0; r < 12; r++) {
                int w = lane + 64 * r;
                int dd = w - bi; if (dd < 0) dd = -dd;
                if (w < WW && dd < 15) m[r] = pen;
            }
        }

        float contrib = 0.f;
        if (lane < 15) {
            int c = lane % 3;
            int g = lane / 3;
            const int offs[5] = {0, -1, 1, -2, 2};
            int nb = best[c] + offs[g];
            nb = min(max(nb, 0), WW - 1);
            float v = s0[nb];
            if (v <= -9900.f) v = 0.f;
            contrib = v * chunk[lane];
        }
        #pragma unroll
        for (int off = 32; off >= 1; off >>= 1) contrib += __shfl_down(contrib, off);
        if (lane == 0) out[b] = contrib;
    }
}

// ---------------------------------------------------------------------------
extern "C" void kernel_launch(void* const* d_in, const int* in_sizes, int n_in,
                              void* d_out, int out_size, void* d_ws, size_t ws_size,
                              hipStream_t stream) {
    const float* qe    = (const float*)d_in[0];   // (8,30,768)
    const float* de    = (const float*)d_in[1];   // (8,1500,768)
    const float* qmask = (const float*)d_in[2];   // (8,30)
    const float* dmask = (const float*)d_in[3];   // (8,1500)
    const float* qidfs = (const float*)d_in[4];   // (8,30,1)
    // d_in[5] = document_idfs (unused)
    const float* mu    = (const float*)d_in[6];   // (11,)
    const float* sigma = (const float*)d_in[7];   // (11,)
    const float* w1    = (const float*)d_in[8];
    const float* b1    = (const float*)d_in[9];
    const float* w2    = (const float*)d_in[10];
    const float* b2    = (const float*)d_in[11];
    const float* w3    = (const float*)d_in[12];
    const float* b3    = (const float*)d_in[13];
    const float* dw    = (const float*)d_in[14];  // (1,11)
    const float* chunk = (const float*)d_in[15];  // (1,15)
    float* out = (float*)d_out;

    float* ws = (float*)d_ws;
    float* cosm   = ws;                      // 240*1500 = 360,000 f32
    float* pscore = ws + 360000;             // 240*736  = 176,640 f32  (~2.1MB)

    skl_gemm<<<dim3(NT, BB), 256, 0, stream>>>(qe, de, cosm);
    skl_windows<<<BB * QQ * 3, 256, 0, stream>>>(cosm, dmask, qmask, qidfs,
                                                 mu, sigma, w1, b1, w2, b2, w3, b3,
                                                 dw, pscore);
    skl_topk<<<BB, 256, 0, stream>>>(pscore, chunk, out);
}